// Round 4
// baseline (390.266 us; speedup 1.0000x reference)
//
#include <hip/hip_runtime.h>

// DenseGINEConv — MI355X (gfx950). B=4, N=512, F=64, H=128, fp32.
// Round 4: structurally-linear two-phase decomposition.
//   Phase 1: block = (b, i-chunk of CI=8). Streams ea[b,i0:i0+8,:,:] (1 MiB)
//            perfectly linearly; accumulates agg over its i's for ALL (j,f)
//            into a 128 KiB LDS accumulator (thread-owned slots, no barriers
//            in the hot loop); writes the (N,F) partial to d_ws.
//   Phase 2: block = (b, 4 j's). Sums 64 chunk-partials, adds self-loop x,
//            fused MLP (W1/b1 lrelu W2/b2), masked write.
// Rationale: rounds 1-3 proved j-parallel (128 KiB-strided) walks are stuck
// at ~2 TB/s while linear fills hit 6.7 TB/s. This removes the stride.

namespace {

constexpr int Bc = 4;
constexpr int Nc = 512;
constexpr int Fc = 64;
constexpr int Hc = 128;
constexpr int CI = 8;                 // i-rows per phase-1 block
constexpr int NCHUNK = Nc / CI;       // 64 chunks per batch
constexpr int TJ = 4;                 // j-rows per phase-2 block
constexpr float NEG = 0.01f;

__device__ __forceinline__ float lrelu(float z) {
  return z > 0.f ? z : z * NEG;
}

// ---------------- Phase 1: linear ea streaming ----------------
__global__ __launch_bounds__(1024, 1) void gine_phase1(
    const float* __restrict__ x,    // (B,N,F)
    const float* __restrict__ adj,  // (B,N,N)
    const float* __restrict__ ea,   // (B,N,N,F)
    float* __restrict__ partial)    // (B, NCHUNK, N, F) in d_ws
{
  const int blk = blockIdx.x;           // 0..255
  const int b   = blk >> 6;
  const int c   = blk & 63;
  const int i0  = c * CI;
  const int tid = threadIdx.x;          // 0..1023

  __shared__ float s_acc[Nc * Fc];      // 128 KiB accumulator for all (j,f)
  __shared__ float s_adj[CI * Nc];      // 16 KiB: adj rows i0..i0+7
  __shared__ float s_x[CI * Fc];        // 2 KiB:  x rows i0..i0+7

  float4* acc4 = reinterpret_cast<float4*>(s_acc);
  const float4 z4 = make_float4(0.f, 0.f, 0.f, 0.f);
  #pragma unroll
  for (int k = 0; k < 8; ++k) acc4[tid + k * 1024] = z4;

  // stage adj (4096 floats) and x (512 floats) for the chunk — coalesced
  reinterpret_cast<float4*>(s_adj)[tid] =
      reinterpret_cast<const float4*>(adj + ((size_t)b * Nc + i0) * Nc)[tid];
  if (tid < CI * Fc / 4)
    reinterpret_cast<float4*>(s_x)[tid] =
        reinterpret_cast<const float4*>(x + ((size_t)b * Nc + i0) * Fc)[tid];
  __syncthreads();

  const float4* eab = reinterpret_cast<const float4*>(ea)
                    + ((size_t)b * Nc + i0) * Nc * (Fc / 4);
  const float4* s_x4 = reinterpret_cast<const float4*>(s_x);

  for (int r = 0; r < CI; ++r) {
    const float4* row = eab + (size_t)r * Nc * (Fc / 4);  // 128 KiB linear
    float4 ev[8];
    #pragma unroll
    for (int k = 0; k < 8; ++k) ev[k] = row[tid + k * 1024];  // 8 loads in flight
    #pragma unroll
    for (int k = 0; k < 8; ++k) {
      const int q  = tid + k * 1024;    // float4 index within (N,F) plane
      const int j  = q >> 4;            // q / (F/4)
      const int fg = q & 15;
      const float a   = s_adj[r * Nc + j];
      const float4 xv = s_x4[r * (Fc / 4) + fg];
      float4 p = acc4[q];               // thread-owned slot: no race, no sync
      p.x += lrelu(a * (xv.x + ev[k].x));
      p.y += lrelu(a * (xv.y + ev[k].y));
      p.z += lrelu(a * (xv.z + ev[k].z));
      p.w += lrelu(a * (xv.w + ev[k].w));
      acc4[q] = p;
    }
  }

  // write the (N,F) partial — linear, coalesced
  float4* part = reinterpret_cast<float4*>(partial) + (size_t)blk * (Nc * Fc / 4);
  #pragma unroll
  for (int k = 0; k < 8; ++k) part[tid + k * 1024] = acc4[tid + k * 1024];
}

// ---------------- Phase 2: chunk-reduce + self-loop + MLP + mask ----------------
__global__ __launch_bounds__(512, 4) void gine_phase2(
    const float* __restrict__ partial,  // (B, NCHUNK, N, F)
    const float* __restrict__ x,        // (B,N,F)
    const int* __restrict__ mask,       // (B,N)
    const float* __restrict__ W1, const float* __restrict__ b1,
    const float* __restrict__ W2, const float* __restrict__ b2,
    float* __restrict__ out)            // (B,N,F)
{
  const int blk = blockIdx.x;           // 0..511
  const int b   = blk >> 7;
  const int j0  = (blk & 127) * TJ;
  const int tid = threadIdx.x;
  const int lane6 = tid & 63;           // (jl, f4): f4 = lane6&15, jl = lane6>>4
  const int f4  = lane6 & 15;
  const int jl  = lane6 >> 4;
  const int cp  = tid >> 6;             // 0..7: chunk-partition

  __shared__ float4 s_part[512];
  __shared__ float  s_out[TJ][Fc];
  __shared__ float  s_hid[TJ][Hc];

  // sum partials over chunks; wave covers 1 KiB contiguous per (c) step
  const float4* pb = reinterpret_cast<const float4*>(partial)
                   + (size_t)(b * NCHUNK) * (Nc * Fc / 4)
                   + (j0 + jl) * (Fc / 4) + f4;
  float4 s = make_float4(0.f, 0.f, 0.f, 0.f);
  #pragma unroll
  for (int c = cp; c < NCHUNK; c += 8) {
    const float4 v = pb[(size_t)c * (Nc * Fc / 4)];
    s.x += v.x; s.y += v.y; s.z += v.z; s.w += v.w;
  }
  s_part[tid] = s;
  __syncthreads();
  #pragma unroll
  for (int st = 256; st >= 64; st >>= 1) {
    if (tid < st) {
      float4 p = s_part[tid];
      const float4 q = s_part[tid + st];
      p.x += q.x; p.y += q.y; p.z += q.z; p.w += q.w;
      s_part[tid] = p;
    }
    __syncthreads();
  }

  const float4* xb4 = reinterpret_cast<const float4*>(x + (size_t)b * Nc * Fc);
  if (tid < 64) {
    const int row = tid >> 4;
    const int fg  = tid & 15;
    float4 r = s_part[tid];
    const float4 xj = xb4[(j0 + row) * (Fc / 4) + fg];
    r.x += xj.x; r.y += xj.y; r.z += xj.z; r.w += xj.w;
    reinterpret_cast<float4*>(&s_out[row][0])[fg] = r;
  }
  __syncthreads();

  // MLP stage 1: all 512 threads
  {
    const int row = tid >> 7;
    const int h   = tid & 127;
    float hv = b1[h];
    #pragma unroll 8
    for (int f = 0; f < Fc; ++f)
      hv = fmaf(s_out[row][f], W1[f * Hc + h], hv);
    s_hid[row][h] = lrelu(hv);
  }
  __syncthreads();

  // MLP stage 2 + mask
  if (tid < TJ * Fc) {
    const int row = tid >> 6;
    const int f   = tid & 63;
    float o = b2[f];
    #pragma unroll 8
    for (int h = 0; h < Hc; ++h)
      o = fmaf(s_hid[row][h], W2[h * Fc + f], o);
    const int rowg = b * Nc + j0 + row;
    out[rowg * Fc + f] = (mask[rowg] != 0) ? o : 0.f;
  }
}

} // namespace

extern "C" void kernel_launch(void* const* d_in, const int* in_sizes, int n_in,
                              void* d_out, int out_size, void* d_ws, size_t ws_size,
                              hipStream_t stream) {
  const float* x    = (const float*)d_in[0];
  const float* adj  = (const float*)d_in[1];
  const float* ea   = (const float*)d_in[2];
  const int*   mask = (const int*)d_in[3];
  const float* W1   = (const float*)d_in[4];
  const float* b1   = (const float*)d_in[5];
  const float* W2   = (const float*)d_in[6];
  const float* b2   = (const float*)d_in[7];
  float* out = (float*)d_out;
  float* partial = (float*)d_ws;   // needs B*NCHUNK*N*F*4 = 32 MiB

  gine_phase1<<<dim3(Bc * NCHUNK), dim3(1024), 0, stream>>>(x, adj, ea, partial);
  gine_phase2<<<dim3(Bc * Nc / TJ), dim3(512), 0, stream>>>(
      partial, x, mask, W1, b1, W2, b2, out);
}

// Round 5
// 379.946 us; speedup vs baseline: 1.0272x; 1.0272x over previous
//
#include <hip/hip_runtime.h>

// DenseGINEConv fused kernel for MI355X (gfx950).
// B=4, N=512, F=64, H=128, fp32. Memory-bound on edge_attr (256 MiB read-once).
// FINAL (revert to Round-2 structure): single fused launch, minimal traffic.
// Session evidence: R2 (1 KiB bursts), R3 (channel rotation), R4 (fully linear
// two-phase, +64 MB traffic) were all neutral-to-negative; R4's +12.7 us
// matches its +64 MB at ~6.3 TB/s -> this kernel already streams ea at the
// achievable-BW roofline (~42-50 us kernel time; the rest of dur_us is
// harness restore/poison, e.g. the 1 GiB 0xAA ws fill at ~160 us).
// Block = (b, j0..j0+3): 512 threads = 8 ip x 4 jl x 16 f4.

namespace {

constexpr int Bc = 4;
constexpr int Nc = 512;
constexpr int Fc = 64;
constexpr int Hc = 128;
constexpr int TJ = 4;          // j-tile per block
constexpr int TH = 512;        // threads per block
constexpr float NEG = 0.01f;

__device__ __forceinline__ float lrelu(float z) {
  return z > 0.f ? z : z * NEG;
}

__global__ __launch_bounds__(TH, 4) void gine_fused(
    const float* __restrict__ x,    // (B,N,F)
    const float* __restrict__ adj,  // (B,N,N)
    const float* __restrict__ ea,   // (B,N,N,F)
    const int* __restrict__ mask,   // (B,N) int32 0/1
    const float* __restrict__ W1,   // (F,H)
    const float* __restrict__ b1,   // (H)
    const float* __restrict__ W2,   // (H,F)
    const float* __restrict__ b2,   // (F)
    float* __restrict__ out)        // (B,N,F)
{
  const int blk = blockIdx.x;            // 0 .. B*N/TJ-1 = 511
  const int b   = blk >> 7;              // blk / (N/TJ = 128)
  const int j0  = (blk & 127) * TJ;
  const int tid = threadIdx.x;
  const int f4  = tid & 15;              // float4 group over F
  const int jl  = (tid >> 4) & 3;        // which j within tile
  const int ip  = tid >> 6;              // 0..7 partial over source i

  __shared__ float4 s_adj4[Nc];          // [i] = adj[b,i,j0..j0+3]
  __shared__ float4 s_part[TH];
  __shared__ float  s_out[TJ][Fc];
  __shared__ float  s_hid[TJ][Hc];

  // ---- stage adj columns j0..j0+3 (8 KiB; L2-shared across tiles) ----
  const float* adjb = adj + (size_t)b * Nc * Nc;
  s_adj4[tid] = *reinterpret_cast<const float4*>(adjb + (size_t)tid * Nc + j0);
  __syncthreads();

  // ---- aggregation: acc[jl][f] = sum_i lrelu(adj[b,i,j0+jl]*(x[b,i,f]+ea[b,i,j0+jl,f])) ----
  const float4* xb4 = reinterpret_cast<const float4*>(x + (size_t)b * Nc * Fc);
  const float4* eap = reinterpret_cast<const float4*>(ea)
                    + ((size_t)b * Nc * Nc + (j0 + jl)) * (Fc / 4) + f4;
  constexpr int ISTRIDE = Nc * Fc / 4;   // 8192 float4s = 128 KiB per i

  float4 acc = make_float4(0.f, 0.f, 0.f, 0.f);
  #pragma unroll 4
  for (int i = ip; i < Nc; i += 8) {
    const float a   = reinterpret_cast<const float*>(&s_adj4[i])[jl]; // broadcast x4
    const float4 xv = xb4[i * (Fc / 4) + f4];                          // L1/L2 hit
    const float4 ev = eap[(size_t)i * ISTRIDE];                        // 1 KiB/wave
    acc.x += lrelu(a * (xv.x + ev.x));
    acc.y += lrelu(a * (xv.y + ev.y));
    acc.z += lrelu(a * (xv.z + ev.z));
    acc.w += lrelu(a * (xv.w + ev.w));
  }

  // ---- reduce 8 ip-partials; partials for (jl,f4) live at stride 64 ----
  s_part[tid] = acc;
  __syncthreads();
  #pragma unroll
  for (int s = 256; s >= 64; s >>= 1) {
    if (tid < s) {
      float4 p = s_part[tid];
      const float4 q = s_part[tid + s];
      p.x += q.x; p.y += q.y; p.z += q.z; p.w += q.w;
      s_part[tid] = p;
    }
    __syncthreads();
  }

  // ---- add self-loop x[b,j,:] (EPS=0), stash 4 rows ----
  if (tid < 64) {
    const int row = tid >> 4;            // 0..3
    const int fg  = tid & 15;
    float4 r = s_part[tid];
    const float4 xj = xb4[(j0 + row) * (Fc / 4) + fg];
    r.x += xj.x; r.y += xj.y; r.z += xj.z; r.w += xj.w;
    reinterpret_cast<float4*>(&s_out[row][0])[fg] = r;
  }
  __syncthreads();

  // ---- MLP stage 1: hid[row][h] = lrelu(row @ W1 + b1); all 512 threads ----
  {
    const int row = tid >> 7;            // 0..3
    const int h   = tid & 127;
    float hv = b1[h];
    #pragma unroll 8
    for (int f = 0; f < Fc; ++f)
      hv = fmaf(s_out[row][f], W1[f * Hc + h], hv);  // coalesced over h
    s_hid[row][h] = lrelu(hv);
  }
  __syncthreads();

  // ---- MLP stage 2: o = hid @ W2 + b2, masked write (256 threads) ----
  if (tid < TJ * Fc) {
    const int row = tid >> 6;            // 0..3
    const int f   = tid & 63;
    float o = b2[f];
    #pragma unroll 8
    for (int h = 0; h < Hc; ++h)
      o = fmaf(s_hid[row][h], W2[h * Fc + f], o);
    const int rowg = b * Nc + j0 + row;
    out[rowg * Fc + f] = (mask[rowg] != 0) ? o : 0.f;
  }
}

} // namespace

extern "C" void kernel_launch(void* const* d_in, const int* in_sizes, int n_in,
                              void* d_out, int out_size, void* d_ws, size_t ws_size,
                              hipStream_t stream) {
  const float* x    = (const float*)d_in[0];
  const float* adj  = (const float*)d_in[1];
  const float* ea   = (const float*)d_in[2];
  const int*   mask = (const int*)d_in[3];
  const float* W1   = (const float*)d_in[4];
  const float* b1   = (const float*)d_in[5];
  const float* W2   = (const float*)d_in[6];
  const float* b2   = (const float*)d_in[7];
  float* out = (float*)d_out;

  gine_fused<<<dim3(Bc * Nc / TJ), dim3(TH), 0, stream>>>(
      x, adj, ea, mask, W1, b1, W2, b2, out);
}